// Round 2
// baseline (2631.394 us; speedup 1.0000x reference)
//
#include <hip/hip_runtime.h>
#include <hip/hip_cooperative_groups.h>
#include <math.h>

namespace cg = cooperative_groups;

#define EPSV 1e-12f
#define BALLC (1.0f - 1e-6f)
#define MAXT 15.0f

// ---------------- mega-kernel ws layout (float offsets) ----------------
#define WS_MU 0
#define WS_P 128
#define WS_Q 256
#define WS_SC 384
#define PART_VEC 512
#define NBMAX 1024
#define PART_ALPHA (PART_VEC + NBMAX * 132)
#define WS_XB (PART_ALPHA + NBMAX)
#define S_MM 0
#define S_PP 1
#define S_QQ 2
#define S_MP 3
#define S_MQ 4
#define S_PQ 5
#define S_TFM 6
#define S_LAMP 7
#define S_KS 8

__device__ __forceinline__ float fast_atanh(float x) {
    return 0.5f * __logf((1.f + x) / (1.f - x));
}
__device__ __forceinline__ float fast_tanh(float x) {
    float e = __expf(-2.f * x);
    return (1.f - e) / (1.f + e);
}
__device__ __forceinline__ float qsum8(float v) {
    v += __shfl_xor(v, 1);
    v += __shfl_xor(v, 2);
    v += __shfl_xor(v, 4);
    return v;
}
__device__ __forceinline__ unsigned pack2_bf16(float a, float b) {
    unsigned ua = __float_as_uint(a), ub = __float_as_uint(b);
    ua += 0x7FFFu + ((ua >> 16) & 1u);
    ub += 0x7FFFu + ((ub >> 16) & 1u);
    return (ua >> 16) | (ub & 0xFFFF0000u);
}
__device__ __forceinline__ float lo_bf16(unsigned u) { return __uint_as_float(u << 16); }
__device__ __forceinline__ float hi_bf16(unsigned u) { return __uint_as_float(u & 0xFFFF0000u); }

// reduce per-lane accumulators across the 8 groups and write block partials
__device__ __forceinline__ void write_partials(float4 acc[4], float accA,
        float lvec[4][128], float lsc[4], float* ws,
        int bid, int tid, int lane, int wv, int sub) {
#pragma unroll
    for (int m = 8; m < 64; m <<= 1) {
#pragma unroll
        for (int k = 0; k < 4; ++k) {
            acc[k].x += __shfl_xor(acc[k].x, m);
            acc[k].y += __shfl_xor(acc[k].y, m);
            acc[k].z += __shfl_xor(acc[k].z, m);
            acc[k].w += __shfl_xor(acc[k].w, m);
        }
        accA += __shfl_xor(accA, m);
    }
    if (lane < 8) {
#pragma unroll
        for (int k = 0; k < 4; ++k) {
            int c = (k * 8 + sub) * 4;
            lvec[wv][c + 0] = acc[k].x;
            lvec[wv][c + 1] = acc[k].y;
            lvec[wv][c + 2] = acc[k].z;
            lvec[wv][c + 3] = acc[k].w;
        }
    }
    if (lane == 0) lsc[wv] = accA;
    __syncthreads();
    if (tid < 128)
        ws[PART_VEC + (size_t)bid * 132 + tid] =
            lvec[0][tid] + lvec[1][tid] + lvec[2][tid] + lvec[3][tid];
    if (tid == 0) ws[PART_ALPHA + bid] = lsc[0] + lsc[1] + lsc[2] + lsc[3];
}

#define TREE128(val, outv)                                   \
    if (tid < 128) lred[tid] = (val);                        \
    __syncthreads();                                         \
    for (int off = 64; off >= 1; off >>= 1) {                \
        if (tid < off) lred[tid] += lred[tid + off];         \
        __syncthreads();                                     \
    }                                                        \
    outv = lred[0];                                          \
    __syncthreads();

// block-0: reduce partials, mu <- expmap(mu, mean_tangent)
__device__ __forceinline__ void update_mu(float* ws, int NB, float invN,
        float lvec[4][128], float lred[128], int tid) {
    float vs = 0.f;
    if (tid < 128) {
#pragma unroll 4
        for (int b = 0; b < NB; ++b) vs += ws[PART_VEC + (size_t)b * 132 + tid];
    } else {
        int j = tid - 128;
        float a = 0.f;
        for (int b = j; b < NB; b += 128) a += ws[PART_ALPHA + b];
        lvec[0][j] = a;
    }
    __syncthreads();
    for (int off = 64; off >= 1; off >>= 1) {
        if (tid < off) lvec[0][tid] += lvec[0][tid + off];
        __syncthreads();
    }
    float atot = lvec[0][0];
    __syncthreads();
    float mm = ws[WS_SC + S_MM];
    float mu_c = 0.f, v = 0.f;
    if (tid < 128) {
        mu_c = ws[WS_MU + tid];
        v = (vs + atot * mu_c) * invN;
    }
    float v2; TREE128(v * v, v2);
    float nv = sqrtf(fmaxf(v2, EPSV));
    float lam = 2.f / fmaxf(1.f - mm, EPSV);
    float arg = fminf(lam * nv * 0.5f, MAXT);
    float tt = fast_tanh(arg);
    float sec = tt * v / nv;
    float xy; TREE128(mu_c * sec, xy);
    float s2n; TREE128(sec * sec, s2n);
    float A = 1.f + 2.f * xy + s2n;
    float B = 1.f - mm;
    float den = fmaxf(1.f + 2.f * xy + mm * s2n, EPSV);
    float munew = (A * mu_c + B * sec) / den;
    float mm2; TREE128(munew * munew, mm2);
    if (tid < 128) ws[WS_MU + tid] = munew;
    if (tid == 0) ws[WS_SC + S_MM] = mm2;
}

// block-0: variance finalize + p, q, Gram scalars
__device__ __forceinline__ void prep_scalars(const float* mpar, const float* vpar,
        float* ws, int NB, float invN, float lred[128], int tid) {
    float vsum = 0.f;
    if (tid < 128)
        for (int b = tid; b < NB; b += 128) vsum += ws[PART_ALPHA + b];
    float varsum; TREE128(vsum, varsum);
    float input_var = varsum * invN;
    float mpv = (tid < 128) ? mpar[tid] : 0.f;
    float mpn2; TREE128(mpv * mpv, mpn2);
    float pn = sqrtf(fmaxf(mpn2, EPSV));
    float p_c = fast_tanh(pn) * mpv / pn;
    float pp; TREE128(p_c * p_c, pp);
    float mu_c = (tid < 128) ? ws[WS_MU + tid] : 0.f;
    float mm = ws[WS_SC + S_MM];
    float pm; TREE128(p_c * mu_c, pm);
    float A = 1.f - 2.f * pm + mm;
    float B = 1.f - pp;
    float den = fmaxf(1.f - 2.f * pm + pp * mm, EPSV);
    float q_c = (B * mu_c - A * p_c) / den;
    float qq; TREE128(q_c * q_c, qq);
    float mq; TREE128(mu_c * q_c, mq);
    float pq; TREE128(p_c * q_c, pq);
    float tfm = fmaxf(1.f - mm, EPSV);
    float tfp = fmaxf(1.f - pp, EPSV);
    float lam_p = 2.f / tfp;
    float svar = sqrtf(vpar[0] / (input_var + 1e-6f));
    float ks = (tfp / tfm) * svar;
    if (tid < 128) {
        ws[WS_P + tid] = p_c;
        ws[WS_Q + tid] = q_c;
    }
    if (tid == 0) {
        ws[WS_SC + S_PP] = pp; ws[WS_SC + S_QQ] = qq; ws[WS_SC + S_MP] = pm;
        ws[WS_SC + S_MQ] = mq; ws[WS_SC + S_PQ] = pq; ws[WS_SC + S_TFM] = tfm;
        ws[WS_SC + S_LAMP] = lam_p; ws[WS_SC + S_KS] = ks;
    }
}

__global__ void __launch_bounds__(256, 4)
mega(const float* __restrict__ x, const float* __restrict__ mpar,
     const float* __restrict__ vpar, float* __restrict__ out,
     float* __restrict__ ws, int N, int use16) {
    cg::grid_group grid = cg::this_grid();
    __shared__ float lvec[4][128];
    __shared__ float lsc[4];
    __shared__ float lred[128];

    const int tid = threadIdx.x;
    const int lane = tid & 63;
    const int wv = tid >> 6;
    const int grp = lane >> 3;
    const int sub = lane & 7;
    const int bid = blockIdx.x;
    const int NB = gridDim.x;
    const int row0 = bid * 32 + wv * 8 + grp;
    const int rstride = NB * 32;
    const float invN = 1.f / (float)N;
    unsigned* xb = (unsigned*)(ws + WS_XB);  // bf16 pairs, 64 uints per row

    // ======== phase A: convert to bf16 + Karcher iteration 0 (mu = 0) ========
    if (bid == 0) {
        if (tid < 128) ws[WS_MU + tid] = 0.f;
        if (tid < 16) ws[WS_SC + tid] = 0.f;
    }
    {
        float4 acc[4];
#pragma unroll
        for (int k = 0; k < 4; ++k) acc[k] = make_float4(0.f, 0.f, 0.f, 0.f);
        for (int r = row0; r < N; r += rstride) {
            const float4* xr = (const float4*)(x + (size_t)r * 128);
            float4 xv[4];
#pragma unroll
            for (int k = 0; k < 4; ++k) xv[k] = xr[k * 8 + sub];
            float np = 0.f;
#pragma unroll
            for (int k = 0; k < 4; ++k)
                np += xv[k].x * xv[k].x + xv[k].y * xv[k].y + xv[k].z * xv[k].z + xv[k].w * xv[k].w;
            float X2 = qsum8(np);
            float n = sqrtf(fmaxf(X2, EPSV));
            float s = fast_atanh(fminf(n, BALLC)) / n;
#pragma unroll
            for (int k = 0; k < 4; ++k) {
                acc[k].x += s * xv[k].x; acc[k].y += s * xv[k].y;
                acc[k].z += s * xv[k].z; acc[k].w += s * xv[k].w;
            }
            if (use16) {
                uint2* xbr = (uint2*)(xb + (size_t)r * 64);
#pragma unroll
                for (int k = 0; k < 4; ++k) {
                    uint2 p;
                    p.x = pack2_bf16(xv[k].x, xv[k].y);
                    p.y = pack2_bf16(xv[k].z, xv[k].w);
                    xbr[k * 8 + sub] = p;
                }
            }
        }
        write_partials(acc, 0.f, lvec, lsc, ws, bid, tid, lane, wv, sub);
    }
    grid.sync();
    if (bid == 0) update_mu(ws, NB, invN, lvec, lred, tid);
    grid.sync();

    // ======== 15 Karcher iterations ========
    for (int it = 0; it < 15; ++it) {
        float mm = ws[WS_SC + S_MM];
        float tfm = fmaxf(1.f - mm, EPSV);
        const float4* mu4 = (const float4*)(ws + WS_MU);
        float4 mur[4];
#pragma unroll
        for (int k = 0; k < 4; ++k) mur[k] = mu4[k * 8 + sub];
        float4 acc[4];
#pragma unroll
        for (int k = 0; k < 4; ++k) acc[k] = make_float4(0.f, 0.f, 0.f, 0.f);
        float accA = 0.f;

#define ROW_BODY()                                                              \
    do {                                                                        \
        float dp = 0.f, np = 0.f;                                               \
        _Pragma("unroll")                                                       \
        for (int k = 0; k < 4; ++k) {                                           \
            dp += mur[k].x * xv[k].x + mur[k].y * xv[k].y +                     \
                  mur[k].z * xv[k].z + mur[k].w * xv[k].w;                      \
            np += xv[k].x * xv[k].x + xv[k].y * xv[k].y +                       \
                  xv[k].z * xv[k].z + xv[k].w * xv[k].w;                        \
        }                                                                       \
        float d = qsum8(dp), X2 = qsum8(np);                                    \
        float A = 1.f - 2.f * d + X2;                                           \
        float Bc = 1.f - mm;                                                    \
        float den = fmaxf(1.f - 2.f * d + mm * X2, EPSV);                       \
        float iv = 1.f / den;                                                   \
        float m2 = (A * A * mm - 2.f * A * Bc * d + Bc * Bc * X2) * iv * iv;    \
        float n = sqrtf(fmaxf(m2, EPSV));                                       \
        float s = tfm * fast_atanh(fminf(n, BALLC)) / n;                        \
        accA += s * (-A * iv);                                                  \
        float delta = s * (Bc * iv);                                            \
        _Pragma("unroll")                                                       \
        for (int k = 0; k < 4; ++k) {                                           \
            acc[k].x += delta * xv[k].x; acc[k].y += delta * xv[k].y;           \
            acc[k].z += delta * xv[k].z; acc[k].w += delta * xv[k].w;           \
        }                                                                       \
    } while (0)

        if (use16) {
            for (int r = row0; r < N; r += rstride) {
                const uint2* xbr = (const uint2*)(xb + (size_t)r * 64);
                float4 xv[4];
#pragma unroll
                for (int k = 0; k < 4; ++k) {
                    uint2 q = xbr[k * 8 + sub];
                    xv[k].x = lo_bf16(q.x); xv[k].y = hi_bf16(q.x);
                    xv[k].z = lo_bf16(q.y); xv[k].w = hi_bf16(q.y);
                }
                ROW_BODY();
            }
        } else {
            for (int r = row0; r < N; r += rstride) {
                const float4* xr = (const float4*)(x + (size_t)r * 128);
                float4 xv[4];
#pragma unroll
                for (int k = 0; k < 4; ++k) xv[k] = xr[k * 8 + sub];
                ROW_BODY();
            }
        }
        write_partials(acc, accA, lvec, lsc, ws, bid, tid, lane, wv, sub);
        grid.sync();
        if (bid == 0) update_mu(ws, NB, invN, lvec, lred, tid);
        grid.sync();
    }

    // ======== variance pass ========
    {
        float mm = ws[WS_SC + S_MM];
        const float4* mu4 = (const float4*)(ws + WS_MU);
        float4 mur[4];
#pragma unroll
        for (int k = 0; k < 4; ++k) mur[k] = mu4[k * 8 + sub];
        float accv = 0.f;
        for (int r = row0; r < N; r += rstride) {
            float4 xv[4];
            if (use16) {
                const uint2* xbr = (const uint2*)(xb + (size_t)r * 64);
#pragma unroll
                for (int k = 0; k < 4; ++k) {
                    uint2 q = xbr[k * 8 + sub];
                    xv[k].x = lo_bf16(q.x); xv[k].y = hi_bf16(q.x);
                    xv[k].z = lo_bf16(q.y); xv[k].w = hi_bf16(q.y);
                }
            } else {
                const float4* xr = (const float4*)(x + (size_t)r * 128);
#pragma unroll
                for (int k = 0; k < 4; ++k) xv[k] = xr[k * 8 + sub];
            }
            float dp = 0.f, np = 0.f;
#pragma unroll
            for (int k = 0; k < 4; ++k) {
                dp += mur[k].x * xv[k].x + mur[k].y * xv[k].y + mur[k].z * xv[k].z + mur[k].w * xv[k].w;
                np += xv[k].x * xv[k].x + xv[k].y * xv[k].y + xv[k].z * xv[k].z + xv[k].w * xv[k].w;
            }
            float d = qsum8(dp), X2 = qsum8(np);
            float A = 1.f - 2.f * d + X2;
            float Bc = 1.f - mm;
            float den = fmaxf(1.f - 2.f * d + mm * X2, EPSV);
            float iv = 1.f / den;
            float m2 = (A * A * mm - 2.f * A * Bc * d + Bc * Bc * X2) * iv * iv;
            float n = sqrtf(fmaxf(m2, EPSV));
            float dist = 2.f * fast_atanh(fminf(n, BALLC));
            accv += dist * dist;
        }
#pragma unroll
        for (int m = 8; m < 64; m <<= 1) accv += __shfl_xor(accv, m);
        if (lane == 0) lsc[wv] = accv;
        __syncthreads();
        if (tid == 0) ws[PART_ALPHA + bid] = lsc[0] + lsc[1] + lsc[2] + lsc[3];
    }
    grid.sync();
    if (bid == 0) prep_scalars(mpar, vpar, ws, NB, invN, lred, tid);
    grid.sync();

    // ======== final pass: out_i = expmap(p, ks * gyr(p,-mu, logmap(mu,x_i))) ========
    {
        const float mm = ws[WS_SC + S_MM], pp = ws[WS_SC + S_PP], qq = ws[WS_SC + S_QQ];
        const float smp = ws[WS_SC + S_MP], smq = ws[WS_SC + S_MQ], spq = ws[WS_SC + S_PQ];
        const float tfm = ws[WS_SC + S_TFM], lam_p = ws[WS_SC + S_LAMP], ks = ws[WS_SC + S_KS];
        const float4* mu4 = (const float4*)(ws + WS_MU);
        const float4* p4 = (const float4*)(ws + WS_P);
        const float4* qv4 = (const float4*)(ws + WS_Q);
        float4 mur[4], pr[4], qr[4];
#pragma unroll
        for (int k = 0; k < 4; ++k) {
            mur[k] = mu4[k * 8 + sub];
            pr[k] = p4[k * 8 + sub];
            qr[k] = qv4[k * 8 + sub];
        }
        for (int r = row0; r < N; r += rstride) {
            const float4* xr = (const float4*)(x + (size_t)r * 128);
            float4 xv[4];
#pragma unroll
            for (int k = 0; k < 4; ++k) xv[k] = xr[k * 8 + sub];
            float am = 0.f, ap = 0.f, aq = 0.f, an = 0.f;
#pragma unroll
            for (int k = 0; k < 4; ++k) {
                am += mur[k].x * xv[k].x + mur[k].y * xv[k].y + mur[k].z * xv[k].z + mur[k].w * xv[k].w;
                ap += pr[k].x * xv[k].x + pr[k].y * xv[k].y + pr[k].z * xv[k].z + pr[k].w * xv[k].w;
                aq += qr[k].x * xv[k].x + qr[k].y * xv[k].y + qr[k].z * xv[k].z + qr[k].w * xv[k].w;
                an += xv[k].x * xv[k].x + xv[k].y * xv[k].y + xv[k].z * xv[k].z + xv[k].w * xv[k].w;
            }
            float Dm = qsum8(am), Dp = qsum8(ap), Dq = qsum8(aq), X2 = qsum8(an);

            float A = 1.f - 2.f * Dm + X2;
            float B = 1.f - mm;
            float den = fmaxf(1.f - 2.f * Dm + mm * X2, EPSV);
            float iv = 1.f / den;
            float m_cm = -A * iv, m_cx = B * iv;
            float m_dm = (-A * mm + B * Dm) * iv;
            float m_dp = (-A * smp + B * Dp) * iv;
            float m_dq = (-A * smq + B * Dq) * iv;
            float m_n2 = (A * A * mm - 2.f * A * B * Dm + B * B * X2) * iv * iv;

            float n1 = sqrtf(fmaxf(m_n2, EPSV));
            float s1 = tfm * fast_atanh(fminf(n1, BALLC)) / n1;
            float t_cm = s1 * m_cm, t_cx = s1 * m_cx;
            float t_dm = s1 * m_dm, t_dp = s1 * m_dp, t_dq = s1 * m_dq;
            float t_n2 = s1 * s1 * m_n2;

            float xy = -t_dm, y2 = t_n2;
            A = 1.f + 2.f * xy + y2;
            B = 1.f - mm;
            den = fmaxf(1.f + 2.f * xy + mm * y2, EPSV);
            iv = 1.f / den;
            float w_cm = (-A + B * t_cm) * iv;
            float w_cx = B * t_cx * iv;
            float w_dp = (-A * smp + B * t_dp) * iv;
            float w_dq = (-A * smq + B * t_dq) * iv;
            float w_n2 = (A * A * mm + 2.f * A * B * xy + B * B * y2) * iv * iv;

            xy = w_dp; y2 = w_n2;
            A = 1.f + 2.f * xy + y2;
            B = 1.f - pp;
            den = fmaxf(1.f + 2.f * xy + pp * y2, EPSV);
            iv = 1.f / den;
            float w2_cm = B * w_cm * iv;
            float w2_cp = A * iv;
            float w2_cx = B * w_cx * iv;
            float w2_dp = (A * pp + B * w_dp) * iv;
            float w2_dq = (A * spq + B * w_dq) * iv;
            float w2_n2 = (A * A * pp + 2.f * A * B * xy + B * B * y2) * iv * iv;

            xy = w2_dq; y2 = w2_n2;
            A = 1.f + 2.f * xy + y2;
            B = 1.f - qq;
            den = fmaxf(1.f + 2.f * xy + qq * y2, EPSV);
            iv = 1.f / den;
            float w3_cm = B * w2_cm * iv;
            float w3_cp = B * w2_cp * iv;
            float w3_cq = A * iv;
            float w3_cx = B * w2_cx * iv;
            float w3_dp = (A * spq + B * w2_dp) * iv;
            float w3_n2 = (A * A * qq + 2.f * A * B * xy + B * B * y2) * iv * iv;

            float u_n2 = ks * ks * w3_n2;
            float nu = sqrtf(fmaxf(u_n2, EPSV));
            float arg = fminf(fmaxf(lam_p * nu * 0.5f, -MAXT), MAXT);
            float sf = fast_tanh(arg) * ks / nu;
            float s_cm = sf * w3_cm, s_cp = sf * w3_cp, s_cq = sf * w3_cq, s_cx = sf * w3_cx;
            float s_dp = sf * w3_dp;
            float s_n2 = sf * sf * w3_n2;

            xy = s_dp; y2 = s_n2;
            A = 1.f + 2.f * xy + y2;
            B = 1.f - pp;
            den = fmaxf(1.f + 2.f * xy + pp * y2, EPSV);
            iv = 1.f / den;
            float o_cm = B * s_cm * iv;
            float o_cp = (A + B * s_cp) * iv;
            float o_cq = B * s_cq * iv;
            float o_cx = B * s_cx * iv;

            float4* orow = (float4*)(out + (size_t)r * 128);
#pragma unroll
            for (int k = 0; k < 4; ++k) {
                float4 o;
                o.x = o_cm * mur[k].x + o_cp * pr[k].x + o_cq * qr[k].x + o_cx * xv[k].x;
                o.y = o_cm * mur[k].y + o_cp * pr[k].y + o_cq * qr[k].y + o_cx * xv[k].y;
                o.z = o_cm * mur[k].z + o_cp * pr[k].z + o_cq * qr[k].z + o_cx * xv[k].z;
                o.w = o_cm * mur[k].w + o_cp * pr[k].w + o_cq * qr[k].w + o_cx * xv[k].w;
                orow[k * 8 + sub] = o;
            }
        }
    }
}

// =====================================================================
// Fallback path (round-1, proven): separate kernels
// =====================================================================
#define FWS_PART 512

__device__ __forceinline__ float qsum4(float v) {
    v += __shfl_xor(v, 1);
    v += __shfl_xor(v, 2);
    return v;
}

__global__ void k_zero(float* ws) {
    int t = threadIdx.x;
    if (t < 128) ws[WS_MU + t] = 0.f;
    if (t < 16) ws[WS_SC + t] = 0.f;
}

__global__ __launch_bounds__(256) void k_acc(const float* __restrict__ x,
                                             const float* __restrict__ ws,
                                             float* __restrict__ part, int N) {
    const float mm = ws[WS_SC + S_MM];
    const float tfm = fmaxf(1.f - mm, EPSV);
    const int lane = threadIdx.x & 63;
    const int wv = threadIdx.x >> 6;
    const int q4 = lane & 3;
    const int gid = blockIdx.x * 64 + (threadIdx.x >> 2);
    const int gstride = gridDim.x * 64;
    const float4* mu4 = (const float4*)(ws + WS_MU);
    float4 mur[8];
#pragma unroll
    for (int k = 0; k < 8; k++) mur[k] = mu4[4 * k + q4];
    float4 acc[8];
#pragma unroll
    for (int k = 0; k < 8; k++) acc[k] = make_float4(0.f, 0.f, 0.f, 0.f);
    float accA = 0.f;
    for (int row = gid; row < N; row += gstride) {
        const float4* xr = (const float4*)(x + (size_t)row * 128);
        float4 xv[8];
#pragma unroll
        for (int k = 0; k < 8; k++) xv[k] = xr[4 * k + q4];
        float dpart = 0.f, npart = 0.f;
#pragma unroll
        for (int k = 0; k < 8; k++) {
            dpart += mur[k].x * xv[k].x + mur[k].y * xv[k].y + mur[k].z * xv[k].z + mur[k].w * xv[k].w;
            npart += xv[k].x * xv[k].x + xv[k].y * xv[k].y + xv[k].z * xv[k].z + xv[k].w * xv[k].w;
        }
        float d = qsum4(dpart);
        float X2 = qsum4(npart);
        float A = 1.f - 2.f * d + X2;
        float B = 1.f - mm;
        float den = fmaxf(1.f - 2.f * d + mm * X2, EPSV);
        float iv = 1.f / den;
        float m2 = (A * A * mm - 2.f * A * B * d + B * B * X2) * iv * iv;
        float n = sqrtf(fmaxf(m2, EPSV));
        float s = tfm * fast_atanh(fminf(n, BALLC)) / n;
        accA += s * (-A * iv);
        float delta = s * (B * iv);
#pragma unroll
        for (int k = 0; k < 8; k++) {
            acc[k].x += delta * xv[k].x;
            acc[k].y += delta * xv[k].y;
            acc[k].z += delta * xv[k].z;
            acc[k].w += delta * xv[k].w;
        }
    }
#pragma unroll
    for (int m = 4; m < 64; m <<= 1) {
#pragma unroll
        for (int k = 0; k < 8; k++) {
            acc[k].x += __shfl_xor(acc[k].x, m);
            acc[k].y += __shfl_xor(acc[k].y, m);
            acc[k].z += __shfl_xor(acc[k].z, m);
            acc[k].w += __shfl_xor(acc[k].w, m);
        }
    }
#pragma unroll
    for (int m = 4; m < 64; m <<= 1) accA += __shfl_xor(accA, m);
    __shared__ float lvec[4][128];
    __shared__ float lalpha[4];
    if (lane < 4) {
#pragma unroll
        for (int k = 0; k < 8; k++) {
            int c = 16 * k + 4 * lane;
            lvec[wv][c + 0] = acc[k].x;
            lvec[wv][c + 1] = acc[k].y;
            lvec[wv][c + 2] = acc[k].z;
            lvec[wv][c + 3] = acc[k].w;
        }
    }
    if (lane == 0) lalpha[wv] = accA;
    __syncthreads();
    int t = threadIdx.x;
    if (t < 128)
        part[(size_t)blockIdx.x * 129 + t] = lvec[0][t] + lvec[1][t] + lvec[2][t] + lvec[3][t];
    if (t == 0)
        part[(size_t)blockIdx.x * 129 + 128] = lalpha[0] + lalpha[1] + lalpha[2] + lalpha[3];
}

__global__ __launch_bounds__(1024) void k_upd(const float* __restrict__ part,
                                              float* __restrict__ ws, int nblk, float invN) {
    __shared__ float lvec[8][128];
    __shared__ float lalpha[8];
    __shared__ float lred[128];
    int t = threadIdx.x;
    int c = t & 127;
    int sg = t >> 7;
    float sum = 0.f;
    for (int b = sg; b < nblk; b += 8) sum += part[(size_t)b * 129 + c];
    lvec[sg][c] = sum;
    if (t < 8) {
        float a = 0.f;
        for (int b = t; b < nblk; b += 8) a += part[(size_t)b * 129 + 128];
        lalpha[t] = a;
    }
    __syncthreads();
    float mm = ws[WS_SC + S_MM];
    float mu_c = 0.f, v = 0.f;
    if (t < 128) {
        float vs = 0.f;
#pragma unroll
        for (int i = 0; i < 8; i++) vs += lvec[i][c];
        float at = 0.f;
#pragma unroll
        for (int i = 0; i < 8; i++) at += lalpha[i];
        mu_c = ws[WS_MU + c];
        v = (vs + at * mu_c) * invN;
    }
    if (t < 128) lred[t] = v * v;
    __syncthreads();
    for (int off = 64; off >= 1; off >>= 1) { if (t < off) lred[t] += lred[t + off]; __syncthreads(); }
    float v2 = lred[0];
    __syncthreads();
    float nv = sqrtf(fmaxf(v2, EPSV));
    float lam = 2.f / fmaxf(1.f - mm, EPSV);
    float arg = fminf(fmaxf(lam * nv * 0.5f, -MAXT), MAXT);
    float tt = fast_tanh(arg);
    float sec = tt * v / nv;
    if (t < 128) lred[t] = mu_c * sec;
    __syncthreads();
    for (int off = 64; off >= 1; off >>= 1) { if (t < off) lred[t] += lred[t + off]; __syncthreads(); }
    float xy = lred[0];
    __syncthreads();
    if (t < 128) lred[t] = sec * sec;
    __syncthreads();
    for (int off = 64; off >= 1; off >>= 1) { if (t < off) lred[t] += lred[t + off]; __syncthreads(); }
    float s2n = lred[0];
    __syncthreads();
    float A = 1.f + 2.f * xy + s2n;
    float B = 1.f - mm;
    float den = fmaxf(1.f + 2.f * xy + mm * s2n, EPSV);
    float munew = (A * mu_c + B * sec) / den;
    if (t < 128) lred[t] = munew * munew;
    __syncthreads();
    for (int off = 64; off >= 1; off >>= 1) { if (t < off) lred[t] += lred[t + off]; __syncthreads(); }
    if (t < 128) ws[WS_MU + t] = munew;
    if (t == 0) ws[WS_SC + S_MM] = lred[0];
}

__global__ __launch_bounds__(256) void k_var(const float* __restrict__ x,
                                             const float* __restrict__ ws,
                                             float* __restrict__ part, int N) {
    const float mm = ws[WS_SC + S_MM];
    const int lane = threadIdx.x & 63;
    const int wv = threadIdx.x >> 6;
    const int q4 = lane & 3;
    const int gid = blockIdx.x * 64 + (threadIdx.x >> 2);
    const int gstride = gridDim.x * 64;
    const float4* mu4 = (const float4*)(ws + WS_MU);
    float4 mur[8];
#pragma unroll
    for (int k = 0; k < 8; k++) mur[k] = mu4[4 * k + q4];
    float accv = 0.f;
    for (int row = gid; row < N; row += gstride) {
        const float4* xr = (const float4*)(x + (size_t)row * 128);
        float4 xv[8];
#pragma unroll
        for (int k = 0; k < 8; k++) xv[k] = xr[4 * k + q4];
        float dpart = 0.f, npart = 0.f;
#pragma unroll
        for (int k = 0; k < 8; k++) {
            dpart += mur[k].x * xv[k].x + mur[k].y * xv[k].y + mur[k].z * xv[k].z + mur[k].w * xv[k].w;
            npart += xv[k].x * xv[k].x + xv[k].y * xv[k].y + xv[k].z * xv[k].z + xv[k].w * xv[k].w;
        }
        float d = qsum4(dpart);
        float X2 = qsum4(npart);
        float A = 1.f - 2.f * d + X2;
        float B = 1.f - mm;
        float den = fmaxf(1.f - 2.f * d + mm * X2, EPSV);
        float iv = 1.f / den;
        float m2 = (A * A * mm - 2.f * A * B * d + B * B * X2) * iv * iv;
        float n = sqrtf(fmaxf(m2, EPSV));
        float dist = 2.f * fast_atanh(fminf(n, BALLC));
        accv += dist * dist;
    }
#pragma unroll
    for (int m = 4; m < 64; m <<= 1) accv += __shfl_xor(accv, m);
    __shared__ float ls[4];
    if (lane == 0) ls[wv] = accv;
    __syncthreads();
    if (threadIdx.x == 0) part[blockIdx.x] = ls[0] + ls[1] + ls[2] + ls[3];
}

__global__ __launch_bounds__(128) void k_prep(const float* __restrict__ mean_param,
                                              const float* __restrict__ var_param,
                                              const float* __restrict__ part,
                                              float* __restrict__ ws, int nblk, float invN) {
    __shared__ float lred[128];
    int t = threadIdx.x;
#define FTREE(val, outv)                                                        \
    lred[t] = (val);                                                            \
    __syncthreads();                                                            \
    for (int off = 64; off >= 1; off >>= 1) {                                   \
        if (t < off) lred[t] += lred[t + off];                                  \
        __syncthreads();                                                        \
    }                                                                           \
    outv = lred[0];                                                             \
    __syncthreads();
    float vs = 0.f;
    for (int b = t; b < nblk; b += 128) vs += part[b];
    float varsum; FTREE(vs, varsum);
    float input_var = varsum * invN;
    float mpv = mean_param[t];
    float mpn2; FTREE(mpv * mpv, mpn2);
    float pn = sqrtf(fmaxf(mpn2, EPSV));
    float p_c = fast_tanh(pn) * mpv / pn;
    float pp; FTREE(p_c * p_c, pp);
    float mu_c = ws[WS_MU + t];
    float mm = ws[WS_SC + S_MM];
    float pm; FTREE(p_c * mu_c, pm);
    float A = 1.f - 2.f * pm + mm;
    float B = 1.f - pp;
    float den = fmaxf(1.f - 2.f * pm + pp * mm, EPSV);
    float q_c = (B * mu_c - A * p_c) / den;
    float qq; FTREE(q_c * q_c, qq);
    float mq; FTREE(mu_c * q_c, mq);
    float pq; FTREE(p_c * q_c, pq);
    float tfm = fmaxf(1.f - mm, EPSV);
    float tfp = fmaxf(1.f - pp, EPSV);
    float lam_p = 2.f / tfp;
    float svar = sqrtf(var_param[0] / (input_var + 1e-6f));
    float ks = (tfp / tfm) * svar;
    ws[WS_P + t] = p_c;
    ws[WS_Q + t] = q_c;
    if (t == 0) {
        ws[WS_SC + S_PP] = pp; ws[WS_SC + S_QQ] = qq; ws[WS_SC + S_MP] = pm;
        ws[WS_SC + S_MQ] = mq; ws[WS_SC + S_PQ] = pq; ws[WS_SC + S_TFM] = tfm;
        ws[WS_SC + S_LAMP] = lam_p; ws[WS_SC + S_KS] = ks;
    }
#undef FTREE
}

__global__ __launch_bounds__(256) void k_out(const float* __restrict__ x,
                                             float* __restrict__ out,
                                             const float* __restrict__ ws, int N) {
    const float mm = ws[WS_SC + S_MM], pp = ws[WS_SC + S_PP], qq = ws[WS_SC + S_QQ];
    const float smp = ws[WS_SC + S_MP], smq = ws[WS_SC + S_MQ], spq = ws[WS_SC + S_PQ];
    const float tfm = ws[WS_SC + S_TFM], lam_p = ws[WS_SC + S_LAMP], ks = ws[WS_SC + S_KS];
    const int lane = threadIdx.x & 63;
    const int q4 = lane & 3;
    const int gid = blockIdx.x * 64 + (threadIdx.x >> 2);
    const int gstride = gridDim.x * 64;
    const float4* mu4 = (const float4*)(ws + WS_MU);
    const float4* p4 = (const float4*)(ws + WS_P);
    const float4* qv4 = (const float4*)(ws + WS_Q);
    float4 mur[8], pr[8], qr[8];
#pragma unroll
    for (int k = 0; k < 8; k++) {
        mur[k] = mu4[4 * k + q4];
        pr[k] = p4[4 * k + q4];
        qr[k] = qv4[4 * k + q4];
    }
    for (int row = gid; row < N; row += gstride) {
        const float4* xr = (const float4*)(x + (size_t)row * 128);
        float4 xv[8];
#pragma unroll
        for (int k = 0; k < 8; k++) xv[k] = xr[4 * k + q4];
        float am = 0.f, ap = 0.f, aq = 0.f, an = 0.f;
#pragma unroll
        for (int k = 0; k < 8; k++) {
            am += mur[k].x * xv[k].x + mur[k].y * xv[k].y + mur[k].z * xv[k].z + mur[k].w * xv[k].w;
            ap += pr[k].x * xv[k].x + pr[k].y * xv[k].y + pr[k].z * xv[k].z + pr[k].w * xv[k].w;
            aq += qr[k].x * xv[k].x + qr[k].y * xv[k].y + qr[k].z * xv[k].z + qr[k].w * xv[k].w;
            an += xv[k].x * xv[k].x + xv[k].y * xv[k].y + xv[k].z * xv[k].z + xv[k].w * xv[k].w;
        }
        float Dm = qsum4(am), Dp = qsum4(ap), Dq = qsum4(aq), X2 = qsum4(an);
        float A = 1.f - 2.f * Dm + X2;
        float B = 1.f - mm;
        float den = fmaxf(1.f - 2.f * Dm + mm * X2, EPSV);
        float iv = 1.f / den;
        float m_cm = -A * iv, m_cx = B * iv;
        float m_dm = (-A * mm + B * Dm) * iv;
        float m_dp = (-A * smp + B * Dp) * iv;
        float m_dq = (-A * smq + B * Dq) * iv;
        float m_n2 = (A * A * mm - 2.f * A * B * Dm + B * B * X2) * iv * iv;
        float n1 = sqrtf(fmaxf(m_n2, EPSV));
        float s1 = tfm * fast_atanh(fminf(n1, BALLC)) / n1;
        float t_cm = s1 * m_cm, t_cx = s1 * m_cx;
        float t_dm = s1 * m_dm, t_dp = s1 * m_dp, t_dq = s1 * m_dq;
        float t_n2 = s1 * s1 * m_n2;
        float xy = -t_dm, y2 = t_n2;
        A = 1.f + 2.f * xy + y2;
        B = 1.f - mm;
        den = fmaxf(1.f + 2.f * xy + mm * y2, EPSV);
        iv = 1.f / den;
        float w_cm = (-A + B * t_cm) * iv;
        float w_cx = B * t_cx * iv;
        float w_dp = (-A * smp + B * t_dp) * iv;
        float w_dq = (-A * smq + B * t_dq) * iv;
        float w_n2 = (A * A * mm + 2.f * A * B * xy + B * B * y2) * iv * iv;
        xy = w_dp; y2 = w_n2;
        A = 1.f + 2.f * xy + y2;
        B = 1.f - pp;
        den = fmaxf(1.f + 2.f * xy + pp * y2, EPSV);
        iv = 1.f / den;
        float w2_cm = B * w_cm * iv;
        float w2_cp = A * iv;
        float w2_cx = B * w_cx * iv;
        float w2_dp = (A * pp + B * w_dp) * iv;
        float w2_dq = (A * spq + B * w_dq) * iv;
        float w2_n2 = (A * A * pp + 2.f * A * B * xy + B * B * y2) * iv * iv;
        xy = w2_dq; y2 = w2_n2;
        A = 1.f + 2.f * xy + y2;
        B = 1.f - qq;
        den = fmaxf(1.f + 2.f * xy + qq * y2, EPSV);
        iv = 1.f / den;
        float w3_cm = B * w2_cm * iv;
        float w3_cp = B * w2_cp * iv;
        float w3_cq = A * iv;
        float w3_cx = B * w2_cx * iv;
        float w3_dp = (A * spq + B * w2_dp) * iv;
        float w3_n2 = (A * A * qq + 2.f * A * B * xy + B * B * y2) * iv * iv;
        float u_n2 = ks * ks * w3_n2;
        float nu = sqrtf(fmaxf(u_n2, EPSV));
        float arg = fminf(fmaxf(lam_p * nu * 0.5f, -MAXT), MAXT);
        float sf = fast_tanh(arg) * ks / nu;
        float s_cm = sf * w3_cm, s_cp = sf * w3_cp, s_cq = sf * w3_cq, s_cx = sf * w3_cx;
        float s_dp = sf * w3_dp;
        float s_n2 = sf * sf * w3_n2;
        xy = s_dp; y2 = s_n2;
        A = 1.f + 2.f * xy + y2;
        B = 1.f - pp;
        den = fmaxf(1.f + 2.f * xy + pp * y2, EPSV);
        iv = 1.f / den;
        float o_cm = B * s_cm * iv;
        float o_cp = (A + B * s_cp) * iv;
        float o_cq = B * s_cq * iv;
        float o_cx = B * s_cx * iv;
        float4* orow = (float4*)(out + (size_t)row * 128);
#pragma unroll
        for (int k = 0; k < 8; k++) {
            float4 o;
            o.x = o_cm * mur[k].x + o_cp * pr[k].x + o_cq * qr[k].x + o_cx * xv[k].x;
            o.y = o_cm * mur[k].y + o_cp * pr[k].y + o_cq * qr[k].y + o_cx * xv[k].y;
            o.z = o_cm * mur[k].z + o_cp * pr[k].z + o_cq * qr[k].z + o_cx * xv[k].z;
            o.w = o_cm * mur[k].w + o_cp * pr[k].w + o_cq * qr[k].w + o_cx * xv[k].w;
            orow[4 * k + q4] = o;
        }
    }
}

extern "C" void kernel_launch(void* const* d_in, const int* in_sizes, int n_in,
                              void* d_out, int out_size, void* d_ws, size_t ws_size,
                              hipStream_t stream) {
    const float* x = (const float*)d_in[0];
    const float* mpar = (const float*)d_in[1];
    const float* vpar = (const float*)d_in[2];
    float* out = (float*)d_out;
    float* ws = (float*)d_ws;
    int N = in_sizes[0] / 128;

    size_t need_base = (size_t)(PART_ALPHA + NBMAX) * sizeof(float);
    size_t need_bf16 = (size_t)WS_XB * sizeof(float) + (size_t)N * 128 * 2;
    int use16 = (ws_size >= need_bf16) ? 1 : 0;

    if (ws_size >= need_base) {
        int dev = 0;
        hipGetDevice(&dev);
        int numCU = 0;
        if (hipDeviceGetAttribute(&numCU, hipDeviceAttributeMultiprocessorCount, dev) != hipSuccess || numCU <= 0)
            numCU = 256;
        int maxb = 0;
        if (hipOccupancyMaxActiveBlocksPerMultiprocessor(&maxb, (const void*)mega, 256, 0) != hipSuccess || maxb <= 0)
            maxb = 2;
        long NBl = (long)maxb * (long)numCU;
        int NB = (NBl > NBMAX) ? NBMAX : (int)NBl;
        void* args[] = {(void*)&x, (void*)&mpar, (void*)&vpar, (void*)&out,
                        (void*)&ws, (void*)&N, (void*)&use16};
        hipError_t e = hipLaunchCooperativeKernel((const void*)mega, dim3(NB), dim3(256),
                                                  args, 0, stream);
        if (e == hipSuccess) return;
    }

    // ---------- fallback: round-1 multi-kernel path ----------
    int nblk = 512;
    size_t need = (size_t)(FWS_PART + nblk * 129) * sizeof(float);
    if (ws_size < need) {
        long avail = ((long)(ws_size / sizeof(float)) - FWS_PART) / 129;
        nblk = (avail < 8) ? 8 : (int)avail;
        if (nblk > 512) nblk = 512;
    }
    float invN = 1.f / (float)N;
    float* part = ws + FWS_PART;
    hipLaunchKernelGGL(k_zero, dim3(1), dim3(128), 0, stream, ws);
    for (int it = 0; it < 16; ++it) {
        hipLaunchKernelGGL(k_acc, dim3(nblk), dim3(256), 0, stream, x, ws, part, N);
        hipLaunchKernelGGL(k_upd, dim3(1), dim3(1024), 0, stream, part, ws, nblk, invN);
    }
    hipLaunchKernelGGL(k_var, dim3(nblk), dim3(256), 0, stream, x, ws, part, N);
    hipLaunchKernelGGL(k_prep, dim3(1), dim3(128), 0, stream, mpar, vpar, part, ws, nblk, invN);
    hipLaunchKernelGGL(k_out, dim3(1024), dim3(256), 0, stream, x, out, ws, N);
}

// Round 3
// 1090.614 us; speedup vs baseline: 2.4128x; 2.4128x over previous
//
#include <hip/hip_runtime.h>
#include <math.h>

#define EPSV 1e-12f
#define BALLC (1.0f - 1e-6f)
#define MAXT 15.0f
#define NBLK 1024

// ws layout (floats); partial/alpha/xb offsets are computed at runtime
#define WS_MU 0
#define WS_P 128
#define WS_Q 256
#define WS_SC 384
#define WS_HDR 512
#define S_MM 0
#define S_PP 1
#define S_QQ 2
#define S_MP 3
#define S_MQ 4
#define S_PQ 5
#define S_TFM 6
#define S_LAMP 7
#define S_KS 8
#define S_FLAG 9

__device__ __forceinline__ float fast_atanh(float x) {
    return 0.5f * __logf((1.f + x) / (1.f - x));
}
__device__ __forceinline__ float fast_tanh(float x) {
    float e = __expf(-2.f * x);
    return (1.f - e) / (1.f + e);
}
__device__ __forceinline__ float qsum4(float v) {
    v += __shfl_xor(v, 1);
    v += __shfl_xor(v, 2);
    return v;
}
__device__ __forceinline__ unsigned pack2_bf16(float a, float b) {
    unsigned ua = __float_as_uint(a), ub = __float_as_uint(b);
    ua += 0x7FFFu + ((ua >> 16) & 1u);
    ub += 0x7FFFu + ((ub >> 16) & 1u);
    return (ua >> 16) | (ub & 0xFFFF0000u);
}
__device__ __forceinline__ float lo_bf16(unsigned u) { return __uint_as_float(u << 16); }
__device__ __forceinline__ float hi_bf16(unsigned u) { return __uint_as_float(u & 0xFFFF0000u); }

__global__ void k_zero(float* ws) {
    int t = threadIdx.x;
    if (t < 128) ws[WS_MU + t] = 0.f;
    if (t < 16) ws[WS_SC + t] = 0.f;
}

// ---------------------------------------------------------------------------
// One Karcher pass. mode: 0 = fp32 read; 1 = fp32 read + bf16 store (pass 0);
// 2 = bf16 read. Lane q4 (4-lane group) owns octets o = 4k+q4 (cols o*8..o*8+7).
// Accumulates sum_i delta_i * x_i (128-vec) and sum_i alpha_i (mu coefficient).
// ---------------------------------------------------------------------------
__global__ __launch_bounds__(256) void k_pass(const float* __restrict__ x,
                                              uint4* __restrict__ xb,
                                              float* __restrict__ ws,
                                              float* __restrict__ part,
                                              float* __restrict__ alpha,
                                              int N, int mode) {
    if (*(volatile const float*)(ws + WS_SC + S_FLAG) != 0.f) return;
    const float mm = ws[WS_SC + S_MM];
    const float tfm = fmaxf(1.f - mm, EPSV);  // = 2/lam(mu)
    const int tid = threadIdx.x;
    const int lane = tid & 63;
    const int wv = tid >> 6;
    const int q4 = lane & 3;
    const int gid = blockIdx.x * 64 + (tid >> 2);
    const int gstride = gridDim.x * 64;

    const float4* mu4 = (const float4*)(ws + WS_MU);
    float4 mur[8];
#pragma unroll
    for (int k = 0; k < 4; ++k) {
        int o = 4 * k + q4;
        mur[2 * k] = mu4[o * 2];
        mur[2 * k + 1] = mu4[o * 2 + 1];
    }
    float4 acc[8];
#pragma unroll
    for (int k = 0; k < 8; ++k) acc[k] = make_float4(0.f, 0.f, 0.f, 0.f);
    float accA = 0.f;

    for (int row = gid; row < N; row += gstride) {
        float4 xv[8];
        if (mode == 2) {
            const uint4* xbr = xb + (size_t)row * 16;
#pragma unroll
            for (int k = 0; k < 4; ++k) {
                uint4 u = xbr[4 * k + q4];
                xv[2 * k].x = lo_bf16(u.x); xv[2 * k].y = hi_bf16(u.x);
                xv[2 * k].z = lo_bf16(u.y); xv[2 * k].w = hi_bf16(u.y);
                xv[2 * k + 1].x = lo_bf16(u.z); xv[2 * k + 1].y = hi_bf16(u.z);
                xv[2 * k + 1].z = lo_bf16(u.w); xv[2 * k + 1].w = hi_bf16(u.w);
            }
        } else {
            const float4* xr = (const float4*)(x + (size_t)row * 128);
#pragma unroll
            for (int k = 0; k < 4; ++k) {
                int o = 4 * k + q4;
                xv[2 * k] = xr[o * 2];
                xv[2 * k + 1] = xr[o * 2 + 1];
            }
            if (mode == 1) {
                uint4* xbr = xb + (size_t)row * 16;
#pragma unroll
                for (int k = 0; k < 4; ++k) {
                    uint4 u;
                    u.x = pack2_bf16(xv[2 * k].x, xv[2 * k].y);
                    u.y = pack2_bf16(xv[2 * k].z, xv[2 * k].w);
                    u.z = pack2_bf16(xv[2 * k + 1].x, xv[2 * k + 1].y);
                    u.w = pack2_bf16(xv[2 * k + 1].z, xv[2 * k + 1].w);
                    xbr[4 * k + q4] = u;
                }
            }
        }
        float dp = 0.f, np = 0.f;
#pragma unroll
        for (int k = 0; k < 8; ++k) {
            dp += mur[k].x * xv[k].x + mur[k].y * xv[k].y + mur[k].z * xv[k].z + mur[k].w * xv[k].w;
            np += xv[k].x * xv[k].x + xv[k].y * xv[k].y + xv[k].z * xv[k].z + xv[k].w * xv[k].w;
        }
        float d = qsum4(dp);
        float X2 = qsum4(np);
        // m = mobius_add(-mu, x): m = (-A*mu + B*x)/den
        float A = 1.f - 2.f * d + X2;
        float B = 1.f - mm;
        float den = fmaxf(1.f - 2.f * d + mm * X2, EPSV);
        float iv = 1.f / den;
        float m2 = (A * A * mm - 2.f * A * B * d + B * B * X2) * iv * iv;
        float n = sqrtf(fmaxf(m2, EPSV));
        float s = tfm * fast_atanh(fminf(n, BALLC)) / n;
        accA += s * (-A * iv);
        float delta = s * (B * iv);
#pragma unroll
        for (int k = 0; k < 8; ++k) {
            acc[k].x += delta * xv[k].x;
            acc[k].y += delta * xv[k].y;
            acc[k].z += delta * xv[k].z;
            acc[k].w += delta * xv[k].w;
        }
    }

    // reduce across the 16 groups of the wave (xor bits 2..5)
#pragma unroll
    for (int m = 4; m < 64; m <<= 1) {
#pragma unroll
        for (int k = 0; k < 8; ++k) {
            acc[k].x += __shfl_xor(acc[k].x, m);
            acc[k].y += __shfl_xor(acc[k].y, m);
            acc[k].z += __shfl_xor(acc[k].z, m);
            acc[k].w += __shfl_xor(acc[k].w, m);
        }
        accA += __shfl_xor(accA, m);
    }
    __shared__ float lvec[4][128];
    __shared__ float lalpha[4];
    if (lane < 4) {
#pragma unroll
        for (int k = 0; k < 4; ++k) {
            int o = 4 * k + lane;
#pragma unroll
            for (int h = 0; h < 2; ++h) {
                int c = o * 8 + 4 * h;
                float4 a = acc[2 * k + h];
                lvec[wv][c + 0] = a.x;
                lvec[wv][c + 1] = a.y;
                lvec[wv][c + 2] = a.z;
                lvec[wv][c + 3] = a.w;
            }
        }
    }
    if (lane == 0) lalpha[wv] = accA;
    __syncthreads();
    if (tid < 128)
        part[(size_t)blockIdx.x * 132 + tid] =
            lvec[0][tid] + lvec[1][tid] + lvec[2][tid] + lvec[3][tid];
    if (tid == 0)
        alpha[blockIdx.x] = lalpha[0] + lalpha[1] + lalpha[2] + lalpha[3];
}

// mu <- expmap(mu, mean_tangent); sets convergence flag when ||dmu||^2 < 1e-12
__global__ __launch_bounds__(1024) void k_upd(float* __restrict__ ws,
                                              const float* __restrict__ part,
                                              const float* __restrict__ alpha,
                                              int nblk, float invN) {
    if (*(volatile const float*)(ws + WS_SC + S_FLAG) != 0.f) return;
    __shared__ float lvec[8][128];
    __shared__ float lalpha[8];
    __shared__ float lred[128];
    int t = threadIdx.x;
    int c = t & 127;
    int sg = t >> 7;
    float s = 0.f;
    for (int b = sg; b < nblk; b += 8) s += part[(size_t)b * 132 + c];
    lvec[sg][c] = s;
    if (t < 8) {
        float a = 0.f;
        for (int b = t; b < nblk; b += 8) a += alpha[b];
        lalpha[t] = a;
    }
    __syncthreads();

#define TREE(val, outv)                                      \
    if (t < 128) lred[t] = (val);                            \
    __syncthreads();                                         \
    for (int off = 64; off >= 1; off >>= 1) {                \
        if (t < off) lred[t] += lred[t + off];               \
        __syncthreads();                                     \
    }                                                        \
    outv = lred[0];                                          \
    __syncthreads();

    float mm = ws[WS_SC + S_MM];
    float mu_c = 0.f, v = 0.f;
    if (t < 128) {
        float vs = 0.f;
#pragma unroll
        for (int i = 0; i < 8; ++i) vs += lvec[i][c];
        float at = 0.f;
#pragma unroll
        for (int i = 0; i < 8; ++i) at += lalpha[i];
        mu_c = ws[WS_MU + c];
        v = (vs + at * mu_c) * invN;
    }
    float v2; TREE(v * v, v2);
    float nv = sqrtf(fmaxf(v2, EPSV));
    float lam = 2.f / fmaxf(1.f - mm, EPSV);
    float arg = fminf(fmaxf(lam * nv * 0.5f, -MAXT), MAXT);
    float tt = fast_tanh(arg);
    float sec = tt * v / nv;
    float xy; TREE(mu_c * sec, xy);
    float s2n; TREE(sec * sec, s2n);
    float A = 1.f + 2.f * xy + s2n;
    float B = 1.f - mm;
    float den = fmaxf(1.f + 2.f * xy + mm * s2n, EPSV);
    float munew = (A * mu_c + B * sec) / den;
    float mm2; TREE(munew * munew, mm2);
    float df = munew - mu_c;
    float stepn2; TREE(df * df, stepn2);
    if (t < 128) ws[WS_MU + t] = munew;
    if (t == 0) {
        ws[WS_SC + S_MM] = mm2;
        if (stepn2 < 1e-12f) ws[WS_SC + S_FLAG] = 1.f;
    }
#undef TREE
}

// variance partials: one float per block into alpha[]
__global__ __launch_bounds__(256) void k_var(const float* __restrict__ x,
                                             const uint4* __restrict__ xb,
                                             const float* __restrict__ ws,
                                             float* __restrict__ alpha,
                                             int N, int mode) {
    const float mm = ws[WS_SC + S_MM];
    const int tid = threadIdx.x;
    const int lane = tid & 63;
    const int wv = tid >> 6;
    const int q4 = lane & 3;
    const int gid = blockIdx.x * 64 + (tid >> 2);
    const int gstride = gridDim.x * 64;
    const float4* mu4 = (const float4*)(ws + WS_MU);
    float4 mur[8];
#pragma unroll
    for (int k = 0; k < 4; ++k) {
        int o = 4 * k + q4;
        mur[2 * k] = mu4[o * 2];
        mur[2 * k + 1] = mu4[o * 2 + 1];
    }
    float accv = 0.f;
    for (int row = gid; row < N; row += gstride) {
        float4 xv[8];
        if (mode == 2) {
            const uint4* xbr = xb + (size_t)row * 16;
#pragma unroll
            for (int k = 0; k < 4; ++k) {
                uint4 u = xbr[4 * k + q4];
                xv[2 * k].x = lo_bf16(u.x); xv[2 * k].y = hi_bf16(u.x);
                xv[2 * k].z = lo_bf16(u.y); xv[2 * k].w = hi_bf16(u.y);
                xv[2 * k + 1].x = lo_bf16(u.z); xv[2 * k + 1].y = hi_bf16(u.z);
                xv[2 * k + 1].z = lo_bf16(u.w); xv[2 * k + 1].w = hi_bf16(u.w);
            }
        } else {
            const float4* xr = (const float4*)(x + (size_t)row * 128);
#pragma unroll
            for (int k = 0; k < 4; ++k) {
                int o = 4 * k + q4;
                xv[2 * k] = xr[o * 2];
                xv[2 * k + 1] = xr[o * 2 + 1];
            }
        }
        float dp = 0.f, np = 0.f;
#pragma unroll
        for (int k = 0; k < 8; ++k) {
            dp += mur[k].x * xv[k].x + mur[k].y * xv[k].y + mur[k].z * xv[k].z + mur[k].w * xv[k].w;
            np += xv[k].x * xv[k].x + xv[k].y * xv[k].y + xv[k].z * xv[k].z + xv[k].w * xv[k].w;
        }
        float d = qsum4(dp);
        float X2 = qsum4(np);
        float A = 1.f - 2.f * d + X2;
        float B = 1.f - mm;
        float den = fmaxf(1.f - 2.f * d + mm * X2, EPSV);
        float iv = 1.f / den;
        float m2 = (A * A * mm - 2.f * A * B * d + B * B * X2) * iv * iv;
        float n = sqrtf(fmaxf(m2, EPSV));
        float dist = 2.f * fast_atanh(fminf(n, BALLC));
        accv += dist * dist;
    }
#pragma unroll
    for (int m = 4; m < 64; m <<= 1) accv += __shfl_xor(accv, m);
    __shared__ float ls[4];
    if (lane == 0) ls[wv] = accv;
    __syncthreads();
    if (tid == 0) alpha[blockIdx.x] = ls[0] + ls[1] + ls[2] + ls[3];
}

// finalize variance; compute p = exp0(mean_param), q = -mobius_add(p,-mu), Gram scalars
__global__ __launch_bounds__(128) void k_prep(const float* __restrict__ mean_param,
                                              const float* __restrict__ var_param,
                                              const float* __restrict__ alpha,
                                              float* __restrict__ ws, int nblk, float invN) {
    __shared__ float lred[128];
    int t = threadIdx.x;
#define FTREE(val, outv)                                     \
    lred[t] = (val);                                         \
    __syncthreads();                                         \
    for (int off = 64; off >= 1; off >>= 1) {                \
        if (t < off) lred[t] += lred[t + off];               \
        __syncthreads();                                     \
    }                                                        \
    outv = lred[0];                                          \
    __syncthreads();

    float vs = 0.f;
    for (int b = t; b < nblk; b += 128) vs += alpha[b];
    float varsum; FTREE(vs, varsum);
    float input_var = varsum * invN;
    float mpv = mean_param[t];
    float mpn2; FTREE(mpv * mpv, mpn2);
    float pn = sqrtf(fmaxf(mpn2, EPSV));
    float p_c = fast_tanh(pn) * mpv / pn;
    float pp; FTREE(p_c * p_c, pp);
    float mu_c = ws[WS_MU + t];
    float mm = ws[WS_SC + S_MM];
    float pm; FTREE(p_c * mu_c, pm);
    float A = 1.f - 2.f * pm + mm;
    float B = 1.f - pp;
    float den = fmaxf(1.f - 2.f * pm + pp * mm, EPSV);
    float q_c = (B * mu_c - A * p_c) / den;
    float qq; FTREE(q_c * q_c, qq);
    float mq; FTREE(mu_c * q_c, mq);
    float pq; FTREE(p_c * q_c, pq);
    float tfm = fmaxf(1.f - mm, EPSV);
    float tfp = fmaxf(1.f - pp, EPSV);
    float lam_p = 2.f / tfp;
    float svar = sqrtf(var_param[0] / (input_var + 1e-6f));
    float ks = (tfp / tfm) * svar;
    ws[WS_P + t] = p_c;
    ws[WS_Q + t] = q_c;
    if (t == 0) {
        ws[WS_SC + S_PP] = pp; ws[WS_SC + S_QQ] = qq; ws[WS_SC + S_MP] = pm;
        ws[WS_SC + S_MQ] = mq; ws[WS_SC + S_PQ] = pq; ws[WS_SC + S_TFM] = tfm;
        ws[WS_SC + S_LAMP] = lam_p; ws[WS_SC + S_KS] = ks;
    }
#undef FTREE
}

// final pass: out_i = expmap(p, ks * gyr(p,-mu, logmap(mu,x_i)))
__global__ __launch_bounds__(256) void k_out(const float* __restrict__ x,
                                             float* __restrict__ out,
                                             const float* __restrict__ ws, int N) {
    const float mm = ws[WS_SC + S_MM], pp = ws[WS_SC + S_PP], qq = ws[WS_SC + S_QQ];
    const float smp = ws[WS_SC + S_MP], smq = ws[WS_SC + S_MQ], spq = ws[WS_SC + S_PQ];
    const float tfm = ws[WS_SC + S_TFM], lam_p = ws[WS_SC + S_LAMP], ks = ws[WS_SC + S_KS];
    const int tid = threadIdx.x;
    const int lane = tid & 63;
    const int q4 = lane & 3;
    const int gid = blockIdx.x * 64 + (tid >> 2);
    const int gstride = gridDim.x * 64;
    const float4* mu4 = (const float4*)(ws + WS_MU);
    const float4* p4 = (const float4*)(ws + WS_P);
    const float4* qv4 = (const float4*)(ws + WS_Q);
    float4 mur[8], pr[8], qr[8];
#pragma unroll
    for (int k = 0; k < 4; ++k) {
        int o = 4 * k + q4;
        mur[2 * k] = mu4[o * 2];     mur[2 * k + 1] = mu4[o * 2 + 1];
        pr[2 * k] = p4[o * 2];       pr[2 * k + 1] = p4[o * 2 + 1];
        qr[2 * k] = qv4[o * 2];      qr[2 * k + 1] = qv4[o * 2 + 1];
    }
    for (int row = gid; row < N; row += gstride) {
        const float4* xr = (const float4*)(x + (size_t)row * 128);
        float4 xv[8];
#pragma unroll
        for (int k = 0; k < 4; ++k) {
            int o = 4 * k + q4;
            xv[2 * k] = xr[o * 2];
            xv[2 * k + 1] = xr[o * 2 + 1];
        }
        float am = 0.f, ap = 0.f, aq = 0.f, an = 0.f;
#pragma unroll
        for (int k = 0; k < 8; ++k) {
            am += mur[k].x * xv[k].x + mur[k].y * xv[k].y + mur[k].z * xv[k].z + mur[k].w * xv[k].w;
            ap += pr[k].x * xv[k].x + pr[k].y * xv[k].y + pr[k].z * xv[k].z + pr[k].w * xv[k].w;
            aq += qr[k].x * xv[k].x + qr[k].y * xv[k].y + qr[k].z * xv[k].z + qr[k].w * xv[k].w;
            an += xv[k].x * xv[k].x + xv[k].y * xv[k].y + xv[k].z * xv[k].z + xv[k].w * xv[k].w;
        }
        float Dm = qsum4(am), Dp = qsum4(ap), Dq = qsum4(aq), X2 = qsum4(an);

        float A = 1.f - 2.f * Dm + X2;
        float B = 1.f - mm;
        float den = fmaxf(1.f - 2.f * Dm + mm * X2, EPSV);
        float iv = 1.f / den;
        float m_cm = -A * iv, m_cx = B * iv;
        float m_dm = (-A * mm + B * Dm) * iv;
        float m_dp = (-A * smp + B * Dp) * iv;
        float m_dq = (-A * smq + B * Dq) * iv;
        float m_n2 = (A * A * mm - 2.f * A * B * Dm + B * B * X2) * iv * iv;

        float n1 = sqrtf(fmaxf(m_n2, EPSV));
        float s1 = tfm * fast_atanh(fminf(n1, BALLC)) / n1;
        float t_cm = s1 * m_cm, t_cx = s1 * m_cx;
        float t_dm = s1 * m_dm, t_dp = s1 * m_dp, t_dq = s1 * m_dq;
        float t_n2 = s1 * s1 * m_n2;

        float xy = -t_dm, y2 = t_n2;
        A = 1.f + 2.f * xy + y2;
        B = 1.f - mm;
        den = fmaxf(1.f + 2.f * xy + mm * y2, EPSV);
        iv = 1.f / den;
        float w_cm = (-A + B * t_cm) * iv;
        float w_cx = B * t_cx * iv;
        float w_dp = (-A * smp + B * t_dp) * iv;
        float w_dq = (-A * smq + B * t_dq) * iv;
        float w_n2 = (A * A * mm + 2.f * A * B * xy + B * B * y2) * iv * iv;

        xy = w_dp; y2 = w_n2;
        A = 1.f + 2.f * xy + y2;
        B = 1.f - pp;
        den = fmaxf(1.f + 2.f * xy + pp * y2, EPSV);
        iv = 1.f / den;
        float w2_cm = B * w_cm * iv;
        float w2_cp = A * iv;
        float w2_cx = B * w_cx * iv;
        float w2_dp = (A * pp + B * w_dp) * iv;
        float w2_dq = (A * spq + B * w_dq) * iv;
        float w2_n2 = (A * A * pp + 2.f * A * B * xy + B * B * y2) * iv * iv;

        xy = w2_dq; y2 = w2_n2;
        A = 1.f + 2.f * xy + y2;
        B = 1.f - qq;
        den = fmaxf(1.f + 2.f * xy + qq * y2, EPSV);
        iv = 1.f / den;
        float w3_cm = B * w2_cm * iv;
        float w3_cp = B * w2_cp * iv;
        float w3_cq = A * iv;
        float w3_cx = B * w2_cx * iv;
        float w3_dp = (A * spq + B * w2_dp) * iv;
        float w3_n2 = (A * A * qq + 2.f * A * B * xy + B * B * y2) * iv * iv;

        float u_n2 = ks * ks * w3_n2;
        float nu = sqrtf(fmaxf(u_n2, EPSV));
        float arg = fminf(fmaxf(lam_p * nu * 0.5f, -MAXT), MAXT);
        float sf = fast_tanh(arg) * ks / nu;
        float s_cm = sf * w3_cm, s_cp = sf * w3_cp, s_cq = sf * w3_cq, s_cx = sf * w3_cx;
        float s_dp = sf * w3_dp;
        float s_n2 = sf * sf * w3_n2;

        xy = s_dp; y2 = s_n2;
        A = 1.f + 2.f * xy + y2;
        B = 1.f - pp;
        den = fmaxf(1.f + 2.f * xy + pp * y2, EPSV);
        iv = 1.f / den;
        float o_cm = B * s_cm * iv;
        float o_cp = (A + B * s_cp) * iv;
        float o_cq = B * s_cq * iv;
        float o_cx = B * s_cx * iv;

        float4* orow = (float4*)(out + (size_t)row * 128);
#pragma unroll
        for (int k = 0; k < 4; ++k) {
            int o = 4 * k + q4;
#pragma unroll
            for (int h = 0; h < 2; ++h) {
                float4 xvk = xv[2 * k + h];
                float4 mk = mur[2 * k + h], pk = pr[2 * k + h], qk = qr[2 * k + h];
                float4 ov;
                ov.x = o_cm * mk.x + o_cp * pk.x + o_cq * qk.x + o_cx * xvk.x;
                ov.y = o_cm * mk.y + o_cp * pk.y + o_cq * qk.y + o_cx * xvk.y;
                ov.z = o_cm * mk.z + o_cp * pk.z + o_cq * qk.z + o_cx * xvk.z;
                ov.w = o_cm * mk.w + o_cp * pk.w + o_cq * qk.w + o_cx * xvk.w;
                orow[o * 2 + h] = ov;
            }
        }
    }
}

extern "C" void kernel_launch(void* const* d_in, const int* in_sizes, int n_in,
                              void* d_out, int out_size, void* d_ws, size_t ws_size,
                              hipStream_t stream) {
    const float* x = (const float*)d_in[0];
    const float* mpar = (const float*)d_in[1];
    const float* vpar = (const float*)d_in[2];
    float* out = (float*)d_out;
    float* ws = (float*)d_ws;
    int N = in_sizes[0] / 128;
    float invN = 1.f / (float)N;

    long wsf = (long)(ws_size / sizeof(float));
    int nblk = NBLK;
    long need = WS_HDR + (long)nblk * 133 + 4;
    if (wsf < need) {
        long nb = (wsf - WS_HDR - 4) / 133;
        nblk = (nb < 8) ? 8 : (int)nb;
        if (nblk > NBLK) nblk = NBLK;
    }
    float* part = ws + WS_HDR;
    float* alpha = part + (long)nblk * 132;
    long off_xb = WS_HDR + (long)nblk * 133;
    off_xb = (off_xb + 3) & ~3L;  // 16B align
    uint4* xb = (uint4*)(ws + off_xb);
    int use16 = (ws_size >= (size_t)off_xb * sizeof(float) + (size_t)N * 256) ? 1 : 0;

    hipLaunchKernelGGL(k_zero, dim3(1), dim3(256), 0, stream, ws);
    // pass 0: mu = 0 (== exp0(mean(log0 x)) init), converts x -> bf16 if room
    hipLaunchKernelGGL(k_pass, dim3(nblk), dim3(256), 0, stream,
                       x, xb, ws, part, alpha, N, use16 ? 1 : 0);
    hipLaunchKernelGGL(k_upd, dim3(1), dim3(1024), 0, stream, ws, part, alpha, nblk, invN);
    for (int it = 1; it < 16; ++it) {
        hipLaunchKernelGGL(k_pass, dim3(nblk), dim3(256), 0, stream,
                           x, xb, ws, part, alpha, N, use16 ? 2 : 0);
        hipLaunchKernelGGL(k_upd, dim3(1), dim3(1024), 0, stream, ws, part, alpha, nblk, invN);
    }
    hipLaunchKernelGGL(k_var, dim3(nblk), dim3(256), 0, stream,
                       x, xb, ws, alpha, N, use16 ? 2 : 0);
    hipLaunchKernelGGL(k_prep, dim3(1), dim3(128), 0, stream, mpar, vpar, alpha, ws, nblk, invN);
    hipLaunchKernelGGL(k_out, dim3(nblk), dim3(256), 0, stream, x, out, ws, N);
}